// Round 5
// baseline (207.422 us; speedup 1.0000x reference)
//
#include <hip/hip_runtime.h>

// logsparseAttention == plain CAUSAL attention (no scale) at L=2048, SUB_LEN=5.
// Q,K,V [B,L,H,D] fp32; Out [B,H,L,D] fp32.  B=4, L=2048, H=16, D=64.
// R10 = R9 with the spill fixed (R9: WRITE_SIZE 33->53MB = scratch writeback):
//  - in-place exp2 (P overwrites S registers; p0/p1 deleted, -32 VGPR)
//  - staggered pack->PV per 32-key half (only one pf pair live, -8 VGPR;
//    softmax VALU of half 1 overlaps PV MFMA of half 0)
//  - everything else as R9: 32x32x16 MFMA, 4-wave blocks, XOR-swizzled K/V,
//    exp2-domain softmax, defer-max, in-register P via cvt_pkrtz +
//    permlane32_swap builtin, double-buffered Ks/Vs (1 barrier/tile),
//    s_setprio(1) around MFMA clusters.

typedef __attribute__((ext_vector_type(8))) short short8;
typedef __attribute__((ext_vector_type(4))) float floatx4;
typedef __attribute__((ext_vector_type(16))) float floatx16;
typedef _Float16 half8 __attribute__((ext_vector_type(8)));
typedef _Float16 half4 __attribute__((ext_vector_type(4)));
typedef unsigned int uint32_t4 __attribute__((ext_vector_type(4)));

#define NB 4
#define NL 2048
#define NH 16
#define ND 64
#define PADK 72   // fallback kernel only
#define LOG2E 1.44269504088896340736f

// swizzled elem index into a [64][64] fp16 tile; col8 must be 8-elem aligned
#define KSW(row, col8) (((row) << 6) + ((col8) ^ (((row) & 7) << 3)))

static __device__ __forceinline__ unsigned short f2bf(float f) {
    unsigned int u = __float_as_uint(f);
    u += 0x7fff + ((u >> 16) & 1);
    return (unsigned short)(u >> 16);
}
static __device__ __forceinline__ float bf2f(unsigned short h) {
    return __uint_as_float(((unsigned int)h) << 16);
}
static __device__ __forceinline__ floatx16 fzero16() {
    floatx16 z;
    #pragma unroll
    for (int i = 0; i < 16; ++i) z[i] = 0.f;
    return z;
}

// cross-half pair exchange: a' = {a.lo32, b.lo32}, b' = {a.hi32, b.hi32}
// (hi = lane>>5, only used by the shuffle fallback)
static __device__ __forceinline__ void plswap2(unsigned int& a, unsigned int& b, int hi) {
#if __has_builtin(__builtin_amdgcn_permlane32_swap)
    auto r = __builtin_amdgcn_permlane32_swap(a, b, false, false);
    a = (unsigned int)r[0];
    b = (unsigned int)r[1];
#else
    const unsigned int ax = (unsigned int)__shfl_xor((int)a, 32);
    const unsigned int bx = (unsigned int)__shfl_xor((int)b, 32);
    const unsigned int na = hi ? bx : a;   // {a.lo, b.lo}
    const unsigned int nb = hi ? b  : ax;  // {a.hi, b.hi}
    a = na; b = nb;
#endif
}
static __device__ __forceinline__ float xhalf_max(float v, int hi) {
    unsigned int a = __float_as_uint(v), b = __float_as_uint(v);
    plswap2(a, b, hi);
    return fmaxf(__uint_as_float(a), __uint_as_float(b));
}
static __device__ __forceinline__ float xhalf_sum(float v, int hi) {
    unsigned int a = __float_as_uint(v), b = __float_as_uint(v);
    plswap2(a, b, hi);
    return __uint_as_float(a) + __uint_as_float(b);
}

// p holds P[q=lq][key = 8s + 4*hi_self + r] in p[4s+r] (s=0..3).
// Produces pfa/pfb = B-operand half8 fragments for two 16-key MFMA chunks:
// pf_c[j] = P[lq][16c + 8*hi_dest + j].
static __device__ __forceinline__ void pack_P(const floatx16& p, int hi, half8& pfa, half8& pfb) {
    unsigned int A0 = __builtin_bit_cast(unsigned int, __builtin_amdgcn_cvt_pkrtz(p[0],  p[1]));
    unsigned int B0 = __builtin_bit_cast(unsigned int, __builtin_amdgcn_cvt_pkrtz(p[2],  p[3]));
    unsigned int A1 = __builtin_bit_cast(unsigned int, __builtin_amdgcn_cvt_pkrtz(p[4],  p[5]));
    unsigned int B1 = __builtin_bit_cast(unsigned int, __builtin_amdgcn_cvt_pkrtz(p[6],  p[7]));
    unsigned int A2 = __builtin_bit_cast(unsigned int, __builtin_amdgcn_cvt_pkrtz(p[8],  p[9]));
    unsigned int B2 = __builtin_bit_cast(unsigned int, __builtin_amdgcn_cvt_pkrtz(p[10], p[11]));
    unsigned int A3 = __builtin_bit_cast(unsigned int, __builtin_amdgcn_cvt_pkrtz(p[12], p[13]));
    unsigned int B3 = __builtin_bit_cast(unsigned int, __builtin_amdgcn_cvt_pkrtz(p[14], p[15]));
    plswap2(A0, A1, hi); plswap2(B0, B1, hi);   // slices (0,1) -> chunk a
    plswap2(A2, A3, hi); plswap2(B2, B3, hi);   // slices (2,3) -> chunk b
    uint32_t4 wa = {A0, B0, A1, B1};
    uint32_t4 wb = {A2, B2, A3, B3};
    pfa = __builtin_bit_cast(half8, wa);
    pfb = __builtin_bit_cast(half8, wb);
}

// ---- fused prepass: K -> Kf [bh][key][d] fp16 * log2(e); V -> Vt [bh][d][key] fp16
__global__ __launch_bounds__(256)
void conv_kv(const float* __restrict__ Kg, const float* __restrict__ Vg,
             _Float16* __restrict__ Kf, _Float16* __restrict__ Vt) {
    __shared__ float tile[64][65];
    const int kt = blockIdx.x;       // key tile 0..31
    const int bh = blockIdx.y;       // 0..63
    const int b  = bh >> 4, h = bh & 15;
    const int t  = threadIdx.x;
    const int row = t >> 2;          // 0..63
    const int seg = (t & 3) * 16;    // 0..48
    const size_t gsrc = (((size_t)(b * NL + kt * 64 + row) * NH + h) << 6) + seg;
    {   // K: vectorized convert, folded log2(e) scale (exp2-domain softmax)
        float kv[16];
        #pragma unroll
        for (int i = 0; i < 16; i += 4) *(float4*)(kv + i) = *(const float4*)(Kg + gsrc + i);
        half8 o0, o1;
        #pragma unroll
        for (int j2 = 0; j2 < 8; ++j2) {
            o0[j2] = (_Float16)(kv[j2] * LOG2E);
            o1[j2] = (_Float16)(kv[8 + j2] * LOG2E);
        }
        _Float16* kd = Kf + (((size_t)(bh * NL + kt * 64 + row)) << 6) + seg;
        *(half8*)kd = o0;
        *(half8*)(kd + 8) = o1;
    }
    {   // V phase 1: fp32 tile into LDS
        #pragma unroll
        for (int i = 0; i < 16; i += 4) {
            float4 v = *(const float4*)(Vg + gsrc + i);
            tile[row][seg + i + 0] = v.x;
            tile[row][seg + i + 1] = v.y;
            tile[row][seg + i + 2] = v.z;
            tile[row][seg + i + 3] = v.w;
        }
    }
    __syncthreads();
    #pragma unroll
    for (int pass = 0; pass < 2; ++pass) {   // V phase 2: transpose out as fp16
        const int d  = pass * 32 + (t >> 3);
        const int kk = (t & 7) * 8;
        half8 o;
        #pragma unroll
        for (int j2 = 0; j2 < 8; ++j2) o[j2] = (_Float16)tile[kk + j2][d];
        *(half8*)(Vt + (((size_t)(bh * 64 + d)) << 11) + kt * 64 + kk) = o;
    }
}

// ------------------------------- main kernel --------------------------------
__global__ __launch_bounds__(256, 4)
void lsattn_main(const float* __restrict__ Qg,
                 const _Float16* __restrict__ Kf,
                 const _Float16* __restrict__ Vt,
                 float* __restrict__ Og) {
    __shared__ alignas(16) _Float16 Ks[2][64 * 64];   // [buf][key][d], swizzled
    __shared__ alignas(16) _Float16 Vs[2][64 * 64];   // [buf][d][key], swizzled

    const int id   = (int)blockIdx.x;        // 0..1023
    const int bh   = id & 63;                // XCD = id%8 -> 8 heads/XCD ~ L2
    const int pr   = id >> 6;                // 0..15
    const int tid  = threadIdx.x;
    const int lane = tid & 63;
    const int w    = tid >> 6;               // wave 0..3
    const int wq   = w & 1;                  // 32-q slice within supertile
    const int lq   = lane & 31;              // query col (C/D: col = lane&31)
    const int hi   = lane >> 5;

    const int sa   = (w < 2) ? pr : 31 - pr; // this wave's 64-q supertile
    const int qrow = sa * 64 + wq * 32 + lq;
    const int TB   = 31 - pr;                // block stages tiles 0..TB (>=16)

    // Q fragments fp32->fp16, B-operand layout: lane holds Q[qrow][c*16+hi*8+j]
    half8 qf[4];
    {
        const float* qp = Qg + (((size_t)((bh >> 4) * NL + qrow) * NH + (bh & 15)) << 6) + hi * 8;
        #pragma unroll
        for (int c = 0; c < 4; ++c) {
            float4 a = *(const float4*)(qp + c * 16);
            float4 b = *(const float4*)(qp + c * 16 + 4);
            qf[c][0] = (_Float16)a.x; qf[c][1] = (_Float16)a.y;
            qf[c][2] = (_Float16)a.z; qf[c][3] = (_Float16)a.w;
            qf[c][4] = (_Float16)b.x; qf[c][5] = (_Float16)b.y;
            qf[c][6] = (_Float16)b.z; qf[c][7] = (_Float16)b.w;
        }
    }

    floatx16 o0 = fzero16(), o1 = fzero16();   // O^T[d 0..31][q], O^T[d 32..63][q]
    float m_run = -1e30f, l_run = 0.f;

    // staging: thread covers 16B of rows srow and srow+32; 256 thr x 4 x 16B = 16KB
    const int srow = tid >> 3;          // 0..31
    const int sseg = (tid & 7) * 8;     // 0..56
    const _Float16* kgb = Kf + ((size_t)bh * NL + srow) * 64 + sseg;               // + t*4096
    const _Float16* vgb = Vt + ((size_t)bh << 17) + (size_t)srow * NL + sseg;      // + t*64

    auto process_tile = [&](int t, const _Float16* Ksb, const _Float16* Vsb) {
        const bool diag  = (t == sa);
        const bool skip1 = diag && (wq == 0);   // upper 32 keys fully masked

        // S^T = K * Q^T : two 32(key) x 32(q) C-tiles, K-dim = D = 64
        floatx16 s0 = fzero16(), s1 = fzero16();
        __builtin_amdgcn_s_setprio(1);
        #pragma unroll
        for (int c = 0; c < 4; ++c) {
            half8 kf = *(const half8*)(Ksb + KSW(lq, c * 16 + hi * 8));
            s0 = __builtin_amdgcn_mfma_f32_32x32x16_f16(kf, qf[c], s0, 0, 0, 0);
        }
        if (!skip1) {
            #pragma unroll
            for (int c = 0; c < 4; ++c) {
                half8 kf = *(const half8*)(Ksb + KSW(32 + lq, c * 16 + hi * 8));
                s1 = __builtin_amdgcn_mfma_f32_32x32x16_f16(kf, qf[c], s1, 0, 0, 0);
            }
        }
        __builtin_amdgcn_s_setprio(0);

        // causal mask on diagonal tile; lane's reg -> key = (r&3)+8*(r>>2)+4*hi
        if (diag) {
            if (wq == 0) {
                #pragma unroll
                for (int reg = 0; reg < 16; ++reg) {
                    const int key = (reg & 3) + ((reg >> 2) << 3) + (hi << 2);
                    if (key > lq) s0[reg] = -1e30f;
                }
            } else {
                #pragma unroll
                for (int reg = 0; reg < 16; ++reg) {
                    const int key = (reg & 3) + ((reg >> 2) << 3) + (hi << 2);
                    if (key > lq) s1[reg] = -1e30f;
                }
            }
        }

        // tile max: tree within lane, then cross-half via permlane swap (VALU)
        float m4[4];
        #pragma unroll
        for (int s = 0; s < 4; ++s)
            m4[s] = fmaxf(fmaxf(s0[4*s], s0[4*s+1]), fmaxf(s0[4*s+2], s0[4*s+3]));
        float mt = fmaxf(fmaxf(m4[0], m4[1]), fmaxf(m4[2], m4[3]));
        if (!skip1) {
            float n4[4];
            #pragma unroll
            for (int s = 0; s < 4; ++s)
                n4[s] = fmaxf(fmaxf(s1[4*s], s1[4*s+1]), fmaxf(s1[4*s+2], s1[4*s+3]));
            mt = fmaxf(mt, fmaxf(fmaxf(n4[0], n4[1]), fmaxf(n4[2], n4[3])));
        }
        mt = xhalf_max(mt, hi);

        if (__any(mt > m_run + 8.f)) {    // defer-max: P bounded by 2^8
            const float mn = fmaxf(m_run, mt);
            const float al = __builtin_amdgcn_exp2f(m_run - mn);
            #pragma unroll
            for (int i = 0; i < 16; ++i) { o0[i] *= al; o1[i] *= al; }
            l_run *= al;
            m_run = mn;
        }

        // half 0: in-place exp2 (P overwrites S regs), sum, pack, PV chunks 0-1
        float ls;
        {
            #pragma unroll
            for (int i = 0; i < 16; ++i) s0[i] = __builtin_amdgcn_exp2f(s0[i] - m_run);
            float t4[4];
            #pragma unroll
            for (int s = 0; s < 4; ++s)
                t4[s] = (s0[4*s] + s0[4*s+1]) + (s0[4*s+2] + s0[4*s+3]);
            ls = (t4[0] + t4[1]) + (t4[2] + t4[3]);

            half8 pfa, pfb;
            pack_P(s0, hi, pfa, pfb);
            __builtin_amdgcn_s_setprio(1);
            #pragma unroll
            for (int c = 0; c < 2; ++c) {
                half8 pf  = (c == 0) ? pfa : pfb;
                half8 vf0 = *(const half8*)(Vsb + KSW(lq,      c * 16 + hi * 8));
                half8 vf1 = *(const half8*)(Vsb + KSW(32 + lq, c * 16 + hi * 8));
                o0 = __builtin_amdgcn_mfma_f32_32x32x16_f16(vf0, pf, o0, 0, 0, 0);
                o1 = __builtin_amdgcn_mfma_f32_32x32x16_f16(vf1, pf, o1, 0, 0, 0);
            }
            __builtin_amdgcn_s_setprio(0);
        }

        // half 1 (if live): same, PV chunks 2-3
        if (!skip1) {
            #pragma unroll
            for (int i = 0; i < 16; ++i) s1[i] = __builtin_amdgcn_exp2f(s1[i] - m_run);
            float u4[4];
            #pragma unroll
            for (int s = 0; s < 4; ++s)
                u4[s] = (s1[4*s] + s1[4*s+1]) + (s1[4*s+2] + s1[4*s+3]);
            ls += (u4[0] + u4[1]) + (u4[2] + u4[3]);

            half8 pfa, pfb;
            pack_P(s1, hi, pfa, pfb);
            __builtin_amdgcn_s_setprio(1);
            #pragma unroll
            for (int c = 2; c < 4; ++c) {
                half8 pf  = (c == 2) ? pfa : pfb;
                half8 vf0 = *(const half8*)(Vsb + KSW(lq,      c * 16 + hi * 8));
                half8 vf1 = *(const half8*)(Vsb + KSW(32 + lq, c * 16 + hi * 8));
                o0 = __builtin_amdgcn_mfma_f32_32x32x16_f16(vf0, pf, o0, 0, 0, 0);
                o1 = __builtin_amdgcn_mfma_f32_32x32x16_f16(vf1, pf, o1, 0, 0, 0);
            }
            __builtin_amdgcn_s_setprio(0);
        }
        l_run += xhalf_sum(ls, hi);
    };

    // prologue: stage tile 0 into buf0, prefetch tile 1 (TB >= 16 so it exists)
    {
        half8 k0 = *(const half8*)(kgb);
        half8 k1 = *(const half8*)(kgb + 2048);
        half8 v0 = *(const half8*)(vgb);
        half8 v1 = *(const half8*)(vgb + 32 * NL);
        *(half8*)(Ks[0] + KSW(srow,      sseg)) = k0;
        *(half8*)(Ks[0] + KSW(srow + 32, sseg)) = k1;
        *(half8*)(Vs[0] + KSW(srow,      sseg)) = v0;
        *(half8*)(Vs[0] + KSW(srow + 32, sseg)) = v1;
    }
    half8 k0 = *(const half8*)(kgb + 4096);
    half8 k1 = *(const half8*)(kgb + 4096 + 2048);
    half8 v0 = *(const half8*)(vgb + 64);
    half8 v1 = *(const half8*)(vgb + 64 + 32 * NL);
    __syncthreads();

    int cur = 0;
    for (int t = 0; t <= TB; ++t) {
        if (t < TB) {
            // write tile t+1 into the other buffer (its last readers passed
            // the barrier at the end of iteration t-1), then prefetch t+2
            _Float16* kd = Ks[cur ^ 1];
            _Float16* vd = Vs[cur ^ 1];
            *(half8*)(kd + KSW(srow,      sseg)) = k0;
            *(half8*)(kd + KSW(srow + 32, sseg)) = k1;
            *(half8*)(vd + KSW(srow,      sseg)) = v0;
            *(half8*)(vd + KSW(srow + 32, sseg)) = v1;
            if (t + 1 < TB) {
                k0 = *(const half8*)(kgb + (size_t)(t + 2) * 4096);
                k1 = *(const half8*)(kgb + (size_t)(t + 2) * 4096 + 2048);
                v0 = *(const half8*)(vgb + (t + 2) * 64);
                v1 = *(const half8*)(vgb + (t + 2) * 64 + 32 * NL);
            }
        }
        if (t <= sa) process_tile(t, Ks[cur], Vs[cur]);
        if (t < TB) __syncthreads();
        cur ^= 1;
    }

    // epilogue: lane holds O[d = 4hi + r + 8s (+32 for o1)][q = lq]
    const float inv = 1.f / l_run;
    float* op = Og + ((size_t)bh * NL + qrow) * ND;
    #pragma unroll
    for (int s = 0; s < 4; ++s) {
        float4 x, y;
        x.x = o0[s * 4 + 0] * inv; x.y = o0[s * 4 + 1] * inv;
        x.z = o0[s * 4 + 2] * inv; x.w = o0[s * 4 + 3] * inv;
        *(float4*)(op + s * 8 + hi * 4) = x;
        y.x = o1[s * 4 + 0] * inv; y.y = o1[s * 4 + 1] * inv;
        y.z = o1[s * 4 + 2] * inv; y.w = o1[s * 4 + 3] * inv;
        *(float4*)(op + 32 + s * 8 + hi * 4) = y;
    }
}

// ===================== fallback (round-2 kernel, passed) =====================
__global__ __launch_bounds__(256)
void lsattn_fb(const float* __restrict__ Qg,
               const float* __restrict__ Kg,
               const float* __restrict__ Vg,
               float* __restrict__ Og) {
    __shared__ alignas(16) unsigned short Kh[64 * PADK];
    __shared__ alignas(16) unsigned short Kl[64 * PADK];
    __shared__ alignas(16) unsigned short Vh[64 * PADK];

    const int qt   = 31 - (int)blockIdx.x;
    const int bh   = blockIdx.y;
    const int tid  = threadIdx.x;
    const int lane = tid & 63;
    const int w    = tid >> 6;
    const int col  = lane & 15;
    const int quad = lane >> 4;
    const int qrow = qt * 64 + w * 16 + col;

    short8 qhi[2], qlo[2];
    {
        const float* qp = Qg + ((bh >> 4) * NL + qrow) * (NH * ND) + (bh & 15) * ND + quad * 8;
        #pragma unroll
        for (int c = 0; c < 2; ++c) {
            float qv[8];
            *(float4*)(qv + 0) = *(const float4*)(qp + c * 32);
            *(float4*)(qv + 4) = *(const float4*)(qp + c * 32 + 4);
            #pragma unroll
            for (int j = 0; j < 8; ++j) {
                unsigned short h = f2bf(qv[j]);
                qhi[c][j] = (short)h;
                qlo[c][j] = (short)f2bf(qv[j] - bf2f(h));
            }
        }
    }
    floatx4 ofrag[4];
    #pragma unroll
    for (int i = 0; i < 4; ++i) ofrag[i] = floatx4{0.f, 0.f, 0.f, 0.f};
    float m_run = -1e30f, l_run = 0.f;
    const int skey  = tid >> 2;
    const int sdb   = (tid & 3) * 16;
    const int gbase = (bh >> 4) * NL * NH * ND + (bh & 15) * ND;

    for (int t = 0; t <= qt; ++t) {
        const int j0 = t * 64;
        __syncthreads();
        {
            const int gro = gbase + (j0 + skey) * (NH * ND) + sdb;
            float kv[16], vv[16];
            #pragma unroll
            for (int i = 0; i < 16; i += 4) {
                *(float4*)(kv + i) = *(const float4*)(Kg + gro + i);
                *(float4*)(vv + i) = *(const float4*)(Vg + gro + i);
            }
            short8 h0, h1, l0, l1;
            #pragma unroll
            for (int j = 0; j < 8; ++j) {
                unsigned short h = f2bf(kv[j]);
                h0[j] = (short)h; l0[j] = (short)f2bf(kv[j] - bf2f(h));
                unsigned short g = f2bf(kv[8 + j]);
                h1[j] = (short)g; l1[j] = (short)f2bf(kv[8 + j] - bf2f(g));
            }
            *(short8*)(Kh + skey * PADK + sdb)     = h0;
            *(short8*)(Kh + skey * PADK + sdb + 8) = h1;
            *(short8*)(Kl + skey * PADK + sdb)     = l0;
            *(short8*)(Kl + skey * PADK + sdb + 8) = l1;
            #pragma unroll
            for (int i = 0; i < 16; ++i) Vh[(sdb + i) * PADK + skey] = f2bf(vv[i]);
        }
        __syncthreads();

        floatx4 stf[4];
        #pragma unroll
        for (int f = 0; f < 4; ++f) {
            floatx4 acc = floatx4{0.f, 0.f, 0.f, 0.f};
            #pragma unroll
            for (int c = 0; c < 2; ++c) {
                short8 kh = *(const short8*)(Kh + (f * 16 + col) * PADK + c * 32 + quad * 8);
                short8 kl = *(const short8*)(Kl + (f * 16 + col) * PADK + c * 32 + quad * 8);
                acc = __builtin_amdgcn_mfma_f32_16x16x32_bf16(kh, qhi[c], acc, 0, 0, 0);
                acc = __builtin_amdgcn_mfma_f32_16x16x32_bf16(kl, qhi[c], acc, 0, 0, 0);
                acc = __builtin_amdgcn_mfma_f32_16x16x32_bf16(kh, qlo[c], acc, 0, 0, 0);
            }
            stf[f] = acc;
        }
        if (t == qt) {
            #pragma unroll
            for (int f = 0; f < 4; ++f)
                #pragma unroll
                for (int r = 0; r < 4; ++r) {
                    const int key = j0 + f * 16 + quad * 4 + r;
                    if (key > qrow) stf[f][r] = -1e30f;
                }
        }
        float mt = -1e30f;
        #pragma unroll
        for (int f = 0; f < 4; ++f)
            #pragma unroll
            for (int r = 0; r < 4; ++r) mt = fmaxf(mt, stf[f][r]);
        mt = fmaxf(mt, __shfl_xor(mt, 16));
        mt = fmaxf(mt, __shfl_xor(mt, 32));
        const float m_new = fmaxf(m_run, mt);
        const float alpha = __expf(m_run - m_new);
        float ls = 0.f;
        #pragma unroll
        for (int f = 0; f < 4; ++f)
            #pragma unroll
            for (int r = 0; r < 4; ++r) {
                const float p = __expf(stf[f][r] - m_new);
                stf[f][r] = p; ls += p;
            }
        ls += __shfl_xor(ls, 16);
        ls += __shfl_xor(ls, 32);
        l_run = l_run * alpha + ls;
        m_run = m_new;
        #pragma unroll
        for (int mc = 0; mc < 4; ++mc) ofrag[mc] *= alpha;

        short8 pfrag[2];
        #pragma unroll
        for (int kc = 0; kc < 2; ++kc) {
            #pragma unroll
            for (int jj = 0; jj < 8; ++jj) {
                const int r  = jj & 3;
                const int sq = (quad & 1) * 2 + (jj >> 2);
                const int sl = col + (sq << 4);
                const float va = __shfl(stf[kc * 2 + 0][r], sl);
                const float vb = __shfl(stf[kc * 2 + 1][r], sl);
                pfrag[kc][jj] = (short)f2bf((quad & 2) ? vb : va);
            }
        }
        #pragma unroll
        for (int mc = 0; mc < 4; ++mc) {
            #pragma unroll
            for (int kc = 0; kc < 2; ++kc) {
                short8 vf = *(const short8*)(Vh + (mc * 16 + col) * PADK + kc * 32 + quad * 8);
                ofrag[mc] = __builtin_amdgcn_mfma_f32_16x16x32_bf16(vf, pfrag[kc], ofrag[mc], 0, 0, 0);
            }
        }
    }
    const float inv = 1.f / l_run;
    float* op = Og + ((size_t)bh * NL + qrow) * ND;
    #pragma unroll
    for (int mc = 0; mc < 4; ++mc) {
        float4 o;
        o.x = ofrag[mc][0] * inv; o.y = ofrag[mc][1] * inv;
        o.z = ofrag[mc][2] * inv; o.w = ofrag[mc][3] * inv;
        *(float4*)(op + mc * 16 + quad * 4) = o;
    }
}

extern "C" void kernel_launch(void* const* d_in, const int* in_sizes, int n_in,
                              void* d_out, int out_size, void* d_ws, size_t ws_size,
                              hipStream_t stream) {
    const float* Q = (const float*)d_in[0];
    const float* K = (const float*)d_in[1];
    const float* V = (const float*)d_in[2];
    float* O = (float*)d_out;

    const size_t elems = (size_t)NB * NL * NH * ND;          // 8,388,608
    if (ws_size >= 2 * elems * sizeof(_Float16)) {           // 32 MiB needed
        _Float16* Kf = (_Float16*)d_ws;
        _Float16* Vt = Kf + elems;
        conv_kv<<<dim3(32, 64), dim3(256), 0, stream>>>(K, V, Kf, Vt);
        lsattn_main<<<dim3(1024), dim3(256), 0, stream>>>(Q, Kf, Vt, O);
    } else {
        lsattn_fb<<<dim3(32, 64), dim3(256), 0, stream>>>(Q, K, V, O);
    }
}

// Round 7
// 192.936 us; speedup vs baseline: 1.0751x; 1.0751x over previous
//
#include <hip/hip_runtime.h>

// logsparseAttention == plain CAUSAL attention (no scale) at L=2048, SUB_LEN=5.
// Q,K,V [B,L,H,D] fp32; Out [B,H,L,D] fp32.  B=4, L=2048, H=16, D=64.
// R12 = R11 + EXPLICIT vmcnt(0) drain before every __syncthreads (T3 recipe;
//       R11's post-timing divergence = race: __syncthreads' implicit drain of
//       global_load_lds DMA writes is not guaranteed by hipcc -> a wave could
//       cross the barrier and ds_read a tile whose DMA hadn't landed).
//  - async staging: 4 x global_load_lds(16B)/thread/tile issued at top of the
//    iteration, drained explicitly at the bottom -> latency hides under the
//    tile's MFMA/softmax. No prefetch registers, no ds_write staging.
//  - swizzle via rule-21 both-sides recipe: linear DMA dest; per-lane GLOBAL
//    source pre-applies the inverse chunk XOR (chunk ^= row&7) so LDS content
//    equals the KSW layout; all KSW readers unchanged.
//  - 32x32x16 MFMA, 4-wave blocks, exp2-domain softmax, defer-max,
//    in-register P (cvt_pkrtz + permlane32_swap), double-buffered Ks/Vs with
//    ONE barrier per tile, s_setprio around MFMA clusters.

typedef __attribute__((ext_vector_type(8))) short short8;
typedef __attribute__((ext_vector_type(4))) float floatx4;
typedef __attribute__((ext_vector_type(16))) float floatx16;
typedef _Float16 half8 __attribute__((ext_vector_type(8)));
typedef _Float16 half4 __attribute__((ext_vector_type(4)));
typedef unsigned int uint32_t4 __attribute__((ext_vector_type(4)));

#define NB 4
#define NL 2048
#define NH 16
#define ND 64
#define PADK 72   // fallback kernel only
#define LOG2E 1.44269504088896340736f

// swizzled elem index into a [64][64] fp16 tile; col8 must be 8-elem aligned
#define KSW(row, col8) (((row) << 6) + ((col8) ^ (((row) & 7) << 3)))

static __device__ __forceinline__ unsigned short f2bf(float f) {
    unsigned int u = __float_as_uint(f);
    u += 0x7fff + ((u >> 16) & 1);
    return (unsigned short)(u >> 16);
}
static __device__ __forceinline__ float bf2f(unsigned short h) {
    return __uint_as_float(((unsigned int)h) << 16);
}
static __device__ __forceinline__ floatx16 fzero16() {
    floatx16 z;
    #pragma unroll
    for (int i = 0; i < 16; ++i) z[i] = 0.f;
    return z;
}

// explicit drain of outstanding VMEM (incl. global_load_lds DMA) + scheduling
// fence (rule 18: keep following ops from hoisting above the wait)
static __device__ __forceinline__ void drain_vmem() {
    asm volatile("s_waitcnt vmcnt(0)" ::: "memory");
    __builtin_amdgcn_sched_barrier(0);
}

// async 16B/lane global->LDS. lds base must be wave-uniform; HW scatters
// lane l's 16B at base + l*16. Global src address is per-lane.
static __device__ __forceinline__ void gload16(const _Float16* g, _Float16* l, int lane) {
#if __has_builtin(__builtin_amdgcn_global_load_lds)
    __builtin_amdgcn_global_load_lds(
        (const __attribute__((address_space(1))) void*)g,
        (__attribute__((address_space(3))) void*)l,
        16, 0, 0);
#else
    *(half8*)(l + lane * 8) = *(const half8*)g;   // emulate base + lane*16B
#endif
}

// cross-half pair exchange: a' = {a.lo32, b.lo32}, b' = {a.hi32, b.hi32}
static __device__ __forceinline__ void plswap2(unsigned int& a, unsigned int& b, int hi) {
#if __has_builtin(__builtin_amdgcn_permlane32_swap)
    auto r = __builtin_amdgcn_permlane32_swap(a, b, false, false);
    a = (unsigned int)r[0];
    b = (unsigned int)r[1];
#else
    const unsigned int ax = (unsigned int)__shfl_xor((int)a, 32);
    const unsigned int bx = (unsigned int)__shfl_xor((int)b, 32);
    const unsigned int na = hi ? bx : a;   // {a.lo, b.lo}
    const unsigned int nb = hi ? b  : ax;  // {a.hi, b.hi}
    a = na; b = nb;
#endif
}
static __device__ __forceinline__ float xhalf_max(float v, int hi) {
    unsigned int a = __float_as_uint(v), b = __float_as_uint(v);
    plswap2(a, b, hi);
    return fmaxf(__uint_as_float(a), __uint_as_float(b));
}
static __device__ __forceinline__ float xhalf_sum(float v, int hi) {
    unsigned int a = __float_as_uint(v), b = __float_as_uint(v);
    plswap2(a, b, hi);
    return __uint_as_float(a) + __uint_as_float(b);
}

// p holds P[q=lq][key = 8s + 4*hi_self + r] in p[4s+r] (s=0..3).
// Produces pfa/pfb = B-operand half8 fragments for two 16-key MFMA chunks:
// pf_c[j] = P[lq][16c + 8*hi_dest + j].
static __device__ __forceinline__ void pack_P(const floatx16& p, int hi, half8& pfa, half8& pfb) {
    unsigned int A0 = __builtin_bit_cast(unsigned int, __builtin_amdgcn_cvt_pkrtz(p[0],  p[1]));
    unsigned int B0 = __builtin_bit_cast(unsigned int, __builtin_amdgcn_cvt_pkrtz(p[2],  p[3]));
    unsigned int A1 = __builtin_bit_cast(unsigned int, __builtin_amdgcn_cvt_pkrtz(p[4],  p[5]));
    unsigned int B1 = __builtin_bit_cast(unsigned int, __builtin_amdgcn_cvt_pkrtz(p[6],  p[7]));
    unsigned int A2 = __builtin_bit_cast(unsigned int, __builtin_amdgcn_cvt_pkrtz(p[8],  p[9]));
    unsigned int B2 = __builtin_bit_cast(unsigned int, __builtin_amdgcn_cvt_pkrtz(p[10], p[11]));
    unsigned int A3 = __builtin_bit_cast(unsigned int, __builtin_amdgcn_cvt_pkrtz(p[12], p[13]));
    unsigned int B3 = __builtin_bit_cast(unsigned int, __builtin_amdgcn_cvt_pkrtz(p[14], p[15]));
    plswap2(A0, A1, hi); plswap2(B0, B1, hi);   // slices (0,1) -> chunk a
    plswap2(A2, A3, hi); plswap2(B2, B3, hi);   // slices (2,3) -> chunk b
    uint32_t4 wa = {A0, B0, A1, B1};
    uint32_t4 wb = {A2, B2, A3, B3};
    pfa = __builtin_bit_cast(half8, wa);
    pfb = __builtin_bit_cast(half8, wb);
}

// ---- fused prepass: K -> Kf [bh][key][d] fp16 * log2(e); V -> Vt [bh][d][key] fp16
__global__ __launch_bounds__(256)
void conv_kv(const float* __restrict__ Kg, const float* __restrict__ Vg,
             _Float16* __restrict__ Kf, _Float16* __restrict__ Vt) {
    __shared__ float tile[64][65];
    const int kt = blockIdx.x;       // key tile 0..31
    const int bh = blockIdx.y;       // 0..63
    const int b  = bh >> 4, h = bh & 15;
    const int t  = threadIdx.x;
    const int row = t >> 2;          // 0..63
    const int seg = (t & 3) * 16;    // 0..48
    const size_t gsrc = (((size_t)(b * NL + kt * 64 + row) * NH + h) << 6) + seg;
    {   // K: vectorized convert, folded log2(e) scale (exp2-domain softmax)
        float kv[16];
        #pragma unroll
        for (int i = 0; i < 16; i += 4) *(float4*)(kv + i) = *(const float4*)(Kg + gsrc + i);
        half8 o0, o1;
        #pragma unroll
        for (int j2 = 0; j2 < 8; ++j2) {
            o0[j2] = (_Float16)(kv[j2] * LOG2E);
            o1[j2] = (_Float16)(kv[8 + j2] * LOG2E);
        }
        _Float16* kd = Kf + (((size_t)(bh * NL + kt * 64 + row)) << 6) + seg;
        *(half8*)kd = o0;
        *(half8*)(kd + 8) = o1;
    }
    {   // V phase 1: fp32 tile into LDS
        #pragma unroll
        for (int i = 0; i < 16; i += 4) {
            float4 v = *(const float4*)(Vg + gsrc + i);
            tile[row][seg + i + 0] = v.x;
            tile[row][seg + i + 1] = v.y;
            tile[row][seg + i + 2] = v.z;
            tile[row][seg + i + 3] = v.w;
        }
    }
    __syncthreads();
    #pragma unroll
    for (int pass = 0; pass < 2; ++pass) {   // V phase 2: transpose out as fp16
        const int d  = pass * 32 + (t >> 3);
        const int kk = (t & 7) * 8;
        half8 o;
        #pragma unroll
        for (int j2 = 0; j2 < 8; ++j2) o[j2] = (_Float16)tile[kk + j2][d];
        *(half8*)(Vt + (((size_t)(bh * 64 + d)) << 11) + kt * 64 + kk) = o;
    }
}

// ------------------------------- main kernel --------------------------------
__global__ __launch_bounds__(256, 4)
void lsattn_main(const float* __restrict__ Qg,
                 const _Float16* __restrict__ Kf,
                 const _Float16* __restrict__ Vt,
                 float* __restrict__ Og) {
    __shared__ alignas(16) _Float16 Ks[2][64 * 64];   // [buf][key][d], swizzled
    __shared__ alignas(16) _Float16 Vs[2][64 * 64];   // [buf][d][key], swizzled

    const int id   = (int)blockIdx.x;        // 0..1023
    const int bh   = id & 63;                // XCD = id%8 -> 8 heads/XCD ~ L2
    const int pr   = id >> 6;                // 0..15
    const int tid  = threadIdx.x;
    const int lane = tid & 63;
    const int w    = tid >> 6;               // wave 0..3
    const int wq   = w & 1;                  // 32-q slice within supertile
    const int lq   = lane & 31;              // query col (C/D: col = lane&31)
    const int hi   = lane >> 5;

    const int sa   = (w < 2) ? pr : 31 - pr; // this wave's 64-q supertile
    const int qrow = sa * 64 + wq * 32 + lq;
    const int TB   = 31 - pr;                // block stages tiles 0..TB (>=16)

    // Q fragments fp32->fp16, B-operand layout: lane holds Q[qrow][c*16+hi*8+j]
    half8 qf[4];
    {
        const float* qp = Qg + (((size_t)((bh >> 4) * NL + qrow) * NH + (bh & 15)) << 6) + hi * 8;
        #pragma unroll
        for (int c = 0; c < 4; ++c) {
            float4 a = *(const float4*)(qp + c * 16);
            float4 b = *(const float4*)(qp + c * 16 + 4);
            qf[c][0] = (_Float16)a.x; qf[c][1] = (_Float16)a.y;
            qf[c][2] = (_Float16)a.z; qf[c][3] = (_Float16)a.w;
            qf[c][4] = (_Float16)b.x; qf[c][5] = (_Float16)b.y;
            qf[c][6] = (_Float16)b.z; qf[c][7] = (_Float16)b.w;
        }
    }

    floatx16 o0 = fzero16(), o1 = fzero16();   // O^T[d 0..31][q], O^T[d 32..63][q]
    float m_run = -1e30f, l_run = 0.f;

    // staging source: thread covers 16B of rows srow and srow+32.
    // Inverse-swizzled chunk (^ row&7) so LINEAR DMA write + KSW read = R10 tile.
    const int srow = tid >> 3;                              // 0..31
    const int sseg = ((tid & 7) ^ ((tid >> 3) & 7)) * 8;    // pre-swizzled chunk
    const _Float16* kg = Kf + ((size_t)bh * NL + srow) * 64 + sseg;              // + t*4096 (+2048)
    const _Float16* vg = Vt + ((size_t)bh << 17) + (size_t)srow * NL + sseg;     // + t*64  (+32*NL)

    // async-stage tile t into buffer buf (4 x 16B per thread, lane-linear dest)
    auto stage = [&](int t, int buf) {
        _Float16* kb = (buf ? (_Float16*)Ks[1] : (_Float16*)Ks[0]) + w * 512;
        _Float16* vb = (buf ? (_Float16*)Vs[1] : (_Float16*)Vs[0]) + w * 512;
        const _Float16* ksrc = kg + (size_t)t * 4096;
        const _Float16* vsrc = vg + t * 64;
        gload16(ksrc,         kb,        lane);
        gload16(ksrc + 2048,  kb + 2048, lane);
        gload16(vsrc,         vb,        lane);
        gload16(vsrc + 65536, vb + 2048, lane);
    };

    auto process_tile = [&](int t, const _Float16* Ksb, const _Float16* Vsb) {
        const bool diag  = (t == sa);
        const bool skip1 = diag && (wq == 0);   // upper 32 keys fully masked

        // S^T = K * Q^T : two 32(key) x 32(q) C-tiles, K-dim = D = 64
        floatx16 s0 = fzero16(), s1 = fzero16();
        __builtin_amdgcn_s_setprio(1);
        #pragma unroll
        for (int c = 0; c < 4; ++c) {
            half8 kf = *(const half8*)(Ksb + KSW(lq, c * 16 + hi * 8));
            s0 = __builtin_amdgcn_mfma_f32_32x32x16_f16(kf, qf[c], s0, 0, 0, 0);
        }
        if (!skip1) {
            #pragma unroll
            for (int c = 0; c < 4; ++c) {
                half8 kf = *(const half8*)(Ksb + KSW(32 + lq, c * 16 + hi * 8));
                s1 = __builtin_amdgcn_mfma_f32_32x32x16_f16(kf, qf[c], s1, 0, 0, 0);
            }
        }
        __builtin_amdgcn_s_setprio(0);

        // causal mask on diagonal tile; lane's reg -> key = (r&3)+8*(r>>2)+4*hi
        if (diag) {
            if (wq == 0) {
                #pragma unroll
                for (int reg = 0; reg < 16; ++reg) {
                    const int key = (reg & 3) + ((reg >> 2) << 3) + (hi << 2);
                    if (key > lq) s0[reg] = -1e30f;
                }
            } else {
                #pragma unroll
                for (int reg = 0; reg < 16; ++reg) {
                    const int key = (reg & 3) + ((reg >> 2) << 3) + (hi << 2);
                    if (key > lq) s1[reg] = -1e30f;
                }
            }
        }

        // tile max: tree within lane, then cross-half via permlane swap (VALU)
        float m4[4];
        #pragma unroll
        for (int s = 0; s < 4; ++s)
            m4[s] = fmaxf(fmaxf(s0[4*s], s0[4*s+1]), fmaxf(s0[4*s+2], s0[4*s+3]));
        float mt = fmaxf(fmaxf(m4[0], m4[1]), fmaxf(m4[2], m4[3]));
        if (!skip1) {
            float n4[4];
            #pragma unroll
            for (int s = 0; s < 4; ++s)
                n4[s] = fmaxf(fmaxf(s1[4*s], s1[4*s+1]), fmaxf(s1[4*s+2], s1[4*s+3]));
            mt = fmaxf(mt, fmaxf(fmaxf(n4[0], n4[1]), fmaxf(n4[2], n4[3])));
        }
        mt = xhalf_max(mt, hi);

        if (__any(mt > m_run + 8.f)) {    // defer-max: P bounded by 2^8
            const float mn = fmaxf(m_run, mt);
            const float al = __builtin_amdgcn_exp2f(m_run - mn);
            #pragma unroll
            for (int i = 0; i < 16; ++i) { o0[i] *= al; o1[i] *= al; }
            l_run *= al;
            m_run = mn;
        }

        // half 0: in-place exp2 (P overwrites S regs), sum, pack, PV chunks 0-1
        float ls;
        {
            #pragma unroll
            for (int i = 0; i < 16; ++i) s0[i] = __builtin_amdgcn_exp2f(s0[i] - m_run);
            float t4[4];
            #pragma unroll
            for (int s = 0; s < 4; ++s)
                t4[s] = (s0[4*s] + s0[4*s+1]) + (s0[4*s+2] + s0[4*s+3]);
            ls = (t4[0] + t4[1]) + (t4[2] + t4[3]);

            half8 pfa, pfb;
            pack_P(s0, hi, pfa, pfb);
            __builtin_amdgcn_s_setprio(1);
            #pragma unroll
            for (int c = 0; c < 2; ++c) {
                half8 pf  = (c == 0) ? pfa : pfb;
                half8 vf0 = *(const half8*)(Vsb + KSW(lq,      c * 16 + hi * 8));
                half8 vf1 = *(const half8*)(Vsb + KSW(32 + lq, c * 16 + hi * 8));
                o0 = __builtin_amdgcn_mfma_f32_32x32x16_f16(vf0, pf, o0, 0, 0, 0);
                o1 = __builtin_amdgcn_mfma_f32_32x32x16_f16(vf1, pf, o1, 0, 0, 0);
            }
            __builtin_amdgcn_s_setprio(0);
        }

        // half 1 (if live): same, PV chunks 2-3
        if (!skip1) {
            #pragma unroll
            for (int i = 0; i < 16; ++i) s1[i] = __builtin_amdgcn_exp2f(s1[i] - m_run);
            float u4[4];
            #pragma unroll
            for (int s = 0; s < 4; ++s)
                u4[s] = (s1[4*s] + s1[4*s+1]) + (s1[4*s+2] + s1[4*s+3]);
            ls += (u4[0] + u4[1]) + (u4[2] + u4[3]);

            half8 pfa, pfb;
            pack_P(s1, hi, pfa, pfb);
            __builtin_amdgcn_s_setprio(1);
            #pragma unroll
            for (int c = 2; c < 4; ++c) {
                half8 pf  = (c == 2) ? pfa : pfb;
                half8 vf0 = *(const half8*)(Vsb + KSW(lq,      c * 16 + hi * 8));
                half8 vf1 = *(const half8*)(Vsb + KSW(32 + lq, c * 16 + hi * 8));
                o0 = __builtin_amdgcn_mfma_f32_32x32x16_f16(vf0, pf, o0, 0, 0, 0);
                o1 = __builtin_amdgcn_mfma_f32_32x32x16_f16(vf1, pf, o1, 0, 0, 0);
            }
            __builtin_amdgcn_s_setprio(0);
        }
        l_run += xhalf_sum(ls, hi);
    };

    // prologue: async-stage tile 0 into buf0; EXPLICIT vmcnt(0) then barrier
    stage(0, 0);
    drain_vmem();
    __syncthreads();

    int cur = 0;
    for (int t = 0; t <= TB; ++t) {
        const _Float16* kcb = cur ? (const _Float16*)Ks[1] : (const _Float16*)Ks[0];
        const _Float16* vcb = cur ? (const _Float16*)Vs[1] : (const _Float16*)Vs[0];
        // issue next tile's async loads into the other buffer (its readers all
        // passed the previous barrier); they fly under this tile's compute
        if (t < TB) stage(t + 1, cur ^ 1);
        if (t <= sa) process_tile(t, kcb, vcb);
        if (t < TB) {
            drain_vmem();      // T3 recipe: DMA writes landed BEFORE the barrier
            __syncthreads();   // buf^1 now visible to all waves
        }
        cur ^= 1;
    }

    // epilogue: lane holds O[d = 4hi + r + 8s (+32 for o1)][q = lq]
    const float inv = 1.f / l_run;
    float* op = Og + ((size_t)bh * NL + qrow) * ND;
    #pragma unroll
    for (int s = 0; s < 4; ++s) {
        float4 x, y;
        x.x = o0[s * 4 + 0] * inv; x.y = o0[s * 4 + 1] * inv;
        x.z = o0[s * 4 + 2] * inv; x.w = o0[s * 4 + 3] * inv;
        *(float4*)(op + s * 8 + hi * 4) = x;
        y.x = o1[s * 4 + 0] * inv; y.y = o1[s * 4 + 1] * inv;
        y.z = o1[s * 4 + 2] * inv; y.w = o1[s * 4 + 3] * inv;
        *(float4*)(op + 32 + s * 8 + hi * 4) = y;
    }
}

// ===================== fallback (round-2 kernel, passed) =====================
__global__ __launch_bounds__(256)
void lsattn_fb(const float* __restrict__ Qg,
               const float* __restrict__ Kg,
               const float* __restrict__ Vg,
               float* __restrict__ Og) {
    __shared__ alignas(16) unsigned short Kh[64 * PADK];
    __shared__ alignas(16) unsigned short Kl[64 * PADK];
    __shared__ alignas(16) unsigned short Vh[64 * PADK];

    const int qt   = 31 - (int)blockIdx.x;
    const int bh   = blockIdx.y;
    const int tid  = threadIdx.x;
    const int lane = tid & 63;
    const int w    = tid >> 6;
    const int col  = lane & 15;
    const int quad = lane >> 4;
    const int qrow = qt * 64 + w * 16 + col;

    short8 qhi[2], qlo[2];
    {
        const float* qp = Qg + ((bh >> 4) * NL + qrow) * (NH * ND) + (bh & 15) * ND + quad * 8;
        #pragma unroll
        for (int c = 0; c < 2; ++c) {
            float qv[8];
            *(float4*)(qv + 0) = *(const float4*)(qp + c * 32);
            *(float4*)(qv + 4) = *(const float4*)(qp + c * 32 + 4);
            #pragma unroll
            for (int j = 0; j < 8; ++j) {
                unsigned short h = f2bf(qv[j]);
                qhi[c][j] = (short)h;
                qlo[c][j] = (short)f2bf(qv[j] - bf2f(h));
            }
        }
    }
    floatx4 ofrag[4];
    #pragma unroll
    for (int i = 0; i < 4; ++i) ofrag[i] = floatx4{0.f, 0.f, 0.f, 0.f};
    float m_run = -1e30f, l_run = 0.f;
    const int skey  = tid >> 2;
    const int sdb   = (tid & 3) * 16;
    const int gbase = (bh >> 4) * NL * NH * ND + (bh & 15) * ND;

    for (int t = 0; t <= qt; ++t) {
        const int j0 = t * 64;
        __syncthreads();
        {
            const int gro = gbase + (j0 + skey) * (NH * ND) + sdb;
            float kv[16], vv[16];
            #pragma unroll
            for (int i = 0; i < 16; i += 4) {
                *(float4*)(kv + i) = *(const float4*)(Kg + gro + i);
                *(float4*)(vv + i) = *(const float4*)(Vg + gro + i);
            }
            short8 h0, h1, l0, l1;
            #pragma unroll
            for (int j = 0; j < 8; ++j) {
                unsigned short h = f2bf(kv[j]);
                h0[j] = (short)h; l0[j] = (short)f2bf(kv[j] - bf2f(h));
                unsigned short g = f2bf(kv[8 + j]);
                h1[j] = (short)g; l1[j] = (short)f2bf(kv[8 + j] - bf2f(g));
            }
            *(short8*)(Kh + skey * PADK + sdb)     = h0;
            *(short8*)(Kh + skey * PADK + sdb + 8) = h1;
            *(short8*)(Kl + skey * PADK + sdb)     = l0;
            *(short8*)(Kl + skey * PADK + sdb + 8) = l1;
            #pragma unroll
            for (int i = 0; i < 16; ++i) Vh[(sdb + i) * PADK + skey] = f2bf(vv[i]);
        }
        __syncthreads();

        floatx4 stf[4];
        #pragma unroll
        for (int f = 0; f < 4; ++f) {
            floatx4 acc = floatx4{0.f, 0.f, 0.f, 0.f};
            #pragma unroll
            for (int c = 0; c < 2; ++c) {
                short8 kh = *(const short8*)(Kh + (f * 16 + col) * PADK + c * 32 + quad * 8);
                short8 kl = *(const short8*)(Kl + (f * 16 + col) * PADK + c * 32 + quad * 8);
                acc = __builtin_amdgcn_mfma_f32_16x16x32_bf16(kh, qhi[c], acc, 0, 0, 0);
                acc = __builtin_amdgcn_mfma_f32_16x16x32_bf16(kl, qhi[c], acc, 0, 0, 0);
                acc = __builtin_amdgcn_mfma_f32_16x16x32_bf16(kh, qlo[c], acc, 0, 0, 0);
            }
            stf[f] = acc;
        }
        if (t == qt) {
            #pragma unroll
            for (int f = 0; f < 4; ++f)
                #pragma unroll
                for (int r = 0; r < 4; ++r) {
                    const int key = j0 + f * 16 + quad * 4 + r;
                    if (key > qrow) stf[f][r] = -1e30f;
                }
        }
        float mt = -1e30f;
        #pragma unroll
        for (int f = 0; f < 4; ++f)
            #pragma unroll
            for (int r = 0; r < 4; ++r) mt = fmaxf(mt, stf[f][r]);
        mt = fmaxf(mt, __shfl_xor(mt, 16));
        mt = fmaxf(mt, __shfl_xor(mt, 32));
        const float m_new = fmaxf(m_run, mt);
        const float alpha = __expf(m_run - m_new);
        float ls = 0.f;
        #pragma unroll
        for (int f = 0; f < 4; ++f)
            #pragma unroll
            for (int r = 0; r < 4; ++r) {
                const float p = __expf(stf[f][r] - m_new);
                stf[f][r] = p; ls += p;
            }
        ls += __shfl_xor(ls, 16);
        ls += __shfl_xor(ls, 32);
        l_run = l_run * alpha + ls;
        m_run = m_new;
        #pragma unroll
        for (int mc = 0; mc < 4; ++mc) ofrag[mc] *= alpha;

        short8 pfrag[2];
        #pragma unroll
        for (int kc = 0; kc < 2; ++kc) {
            #pragma unroll
            for (int jj = 0; jj < 8; ++jj) {
                const int r  = jj & 3;
                const int sq = (quad & 1) * 2 + (jj >> 2);
                const int sl = col + (sq << 4);
                const float va = __shfl(stf[kc * 2 + 0][r], sl);
                const float vb = __shfl(stf[kc * 2 + 1][r], sl);
                pfrag[kc][jj] = (short)f2bf((quad & 2) ? vb : va);
            }
        }
        #pragma unroll
        for (int mc = 0; mc < 4; ++mc) {
            #pragma unroll
            for (int kc = 0; kc < 2; ++kc) {
                short8 vf = *(const short8*)(Vh + (mc * 16 + col) * PADK + kc * 32 + quad * 8);
                ofrag[mc] = __builtin_amdgcn_mfma_f32_16x16x32_bf16(vf, pfrag[kc], ofrag[mc], 0, 0, 0);
            }
        }
    }
    const float inv = 1.f / l_run;
    float* op = Og + ((size_t)bh * NL + qrow) * ND;
    #pragma unroll
    for (int mc = 0; mc < 4; ++mc) {
        float4 o;
        o.x = ofrag[mc][0] * inv; o.y = ofrag[mc][1] * inv;
        o.z = ofrag[mc][2] * inv; o.w = ofrag[mc][3] * inv;
        *(float4*)(op + mc * 16 + quad * 4) = o;
    }
}

extern "C" void kernel_launch(void* const* d_in, const int* in_sizes, int n_in,
                              void* d_out, int out_size, void* d_ws, size_t ws_size,
                              hipStream_t stream) {
    const float* Q = (const float*)d_in[0];
    const float* K = (const float*)d_in[1];
    const float* V = (const float*)d_in[2];
    float* O = (float*)d_out;

    const size_t elems = (size_t)NB * NL * NH * ND;          // 8,388,608
    if (ws_size >= 2 * elems * sizeof(_Float16)) {           // 32 MiB needed
        _Float16* Kf = (_Float16*)d_ws;
        _Float16* Vt = Kf + elems;
        conv_kv<<<dim3(32, 64), dim3(256), 0, stream>>>(K, V, Kf, Vt);
        lsattn_main<<<dim3(1024), dim3(256), 0, stream>>>(Q, Kf, Vt, O);
    } else {
        lsattn_fb<<<dim3(32, 64), dim3(256), 0, stream>>>(Q, K, V, O);
    }
}